// Round 7
// baseline (863.939 us; speedup 1.0000x reference)
//
#include <hip/hip_runtime.h>
#include <hip/hip_cooperative_groups.h>
#include <math.h>

namespace cg = cooperative_groups;

// ETM forward. B=1024 S=512 V=50000 E=300 H=800 T=50.
// SINGLE persistent cooperative kernel, 6 grid-stride phases + grid.sync():
//  P0: rhoh=bf16(rho) cast + zero topicsumR/loss + MFMA B-frags
//  P1: k4 betaU=exp(rhoh@alpha^T) (XCD-affine slices) + k1 sliced gather
//  P2: xsg = bf16((sum_r xbarP)/n)
//  P3: hbh = bf16(relu(xsg@W1+b1))   (832 units - full parallelism)
//  P4: mu/lv MFMA -> softmax/theta/kl
//  P5: recon + loss
// Rationale: r0-r6 showed ~90us of the 200us total is unexplained by any
// phase roofline -> per-launch/drain overhead of 5-6 stream-serialized
// dispatches. Persistent kernel removes all launch boundaries.
// NT stores reverted (r6: they evicted consumers' inputs); NT ids loads kept.

#define Bn 1024
#define Sn 512
#define Vn 50000
#define En 300
#define Hn 800
#define Tn 50
#define KP 320
#define BSTR 64
#define W1FRAG_N (50 * 10 * 64 * 8)     // 256000
#define WFRAG_N  (8 * 25 * 64 * 8)      // 102400
#define NRANGE 8
#define CASTB 7813                       // ceil(Vn*(KP/8)/256)
#define K4B 3128                         // 8 x 391 (3125 tiles + 3 idle)
#define P1UNITS (K4B + Bn * NRANGE)

// workspace byte offsets
#define O_TOPIC   0u
#define O_BFRAG   2048u
#define O_W1FRAG  43008u
#define O_WFRAG   555008u
#define O_CNT     759808u
#define O_TOKS    763904u
#define O_XBARP   2861056u
#define O_HBH     13346816u
#define O_XSG     14985216u
#define O_RHOH    15640576u
#define O_BETAU   47640576u

typedef __bf16 bf16x8 __attribute__((ext_vector_type(8)));
typedef float  f32x4  __attribute__((ext_vector_type(4)));
typedef float  f32x2  __attribute__((ext_vector_type(2)));

__device__ __forceinline__ float waveReduceSum(float v) {
    #pragma unroll
    for (int off = 32; off > 0; off >>= 1) v += __shfl_xor(v, off, 64);
    return v;
}
__device__ __forceinline__ float waveReduceMax(float v) {
    #pragma unroll
    for (int off = 32; off > 0; off >>= 1) v = fmaxf(v, __shfl_xor(v, off, 64));
    return v;
}
__device__ __forceinline__ unsigned short f2bf(float x) {
    unsigned u = __float_as_uint(x);
    return (unsigned short)((u + 0x7FFFu + ((u >> 16) & 1u)) >> 16);
}
__device__ __forceinline__ float bf_lo(unsigned u) { return __uint_as_float(u << 16); }
__device__ __forceinline__ float bf_hi(unsigned u) { return __uint_as_float(u & 0xFFFF0000u); }
__device__ __forceinline__ int lane_prefix(unsigned long long m) {
    return __builtin_amdgcn_mbcnt_hi((unsigned)(m >> 32),
           __builtin_amdgcn_mbcnt_lo((unsigned)m, 0));
}

#define PKACC(u) { \
    c0 += (f32x2){bf_lo((u).x), bf_hi((u).x)}; \
    c1 += (f32x2){bf_lo((u).y), bf_hi((u).y)}; \
    c2 += (f32x2){bf_lo((u).z), bf_hi((u).z)}; \
    c3 += (f32x2){bf_lo((u).w), bf_hi((u).w)}; }

__global__ __launch_bounds__(256, 8) void kmega(
        const int* __restrict__ ids, const float4* __restrict__ rho4,
        const float* __restrict__ alpha, const float* __restrict__ W1,
        const float* __restrict__ b1, const float* __restrict__ Wmu,
        const float* __restrict__ bmu, const float* __restrict__ Wlv,
        const float* __restrict__ blv, float* __restrict__ theta,
        float* __restrict__ loss, char* __restrict__ ws) {
    cg::grid_group grid = cg::this_grid();
    __shared__ __align__(16) char smem[10496];
    __shared__ int scount, sfull;

    float* topicsumR       = (float*)(ws + O_TOPIC);
    unsigned short* bfrag  = (unsigned short*)(ws + O_BFRAG);
    unsigned short* w1frag = (unsigned short*)(ws + O_W1FRAG);
    unsigned short* wfrag  = (unsigned short*)(ws + O_WFRAG);
    int* cnt               = (int*)(ws + O_CNT);
    int* toks              = (int*)(ws + O_TOKS);
    float* xbarP           = (float*)(ws + O_XBARP);
    unsigned short* hbh    = (unsigned short*)(ws + O_HBH);
    unsigned short* xsg    = (unsigned short*)(ws + O_XSG);
    unsigned short* rhoh   = (unsigned short*)(ws + O_RHOH);
    unsigned int* betaU32  = (unsigned int*)(ws + O_BETAU);

    const int tid = threadIdx.x;
    const int wave = tid >> 6, lane = tid & 63;
    const int quad = lane >> 4, l15 = lane & 15;
    const int G = gridDim.x, bid = blockIdx.x;

    // ---------------- P0: cast + zero + frags ----------------
    for (int u = bid; u < CASTB + 1400; u += G) {
        if (u < CASTB) {
            const int i = u * 256 + tid;
            if (i < Vn * (KP / 8)) {
                int v = i / (KP / 8), s8 = i - v * (KP / 8);
                int c = s8 * 8;
                ushort4 o0 = {0, 0, 0, 0}, o1 = {0, 0, 0, 0};
                if (c < En) {
                    float4 r = rho4[v * (En / 4) + s8 * 2];
                    o0.x = f2bf(r.x); o0.y = f2bf(r.y); o0.z = f2bf(r.z); o0.w = f2bf(r.w);
                }
                if (c + 4 < En) {
                    float4 r = rho4[v * (En / 4) + s8 * 2 + 1];
                    o1.x = f2bf(r.x); o1.y = f2bf(r.y); o1.z = f2bf(r.z); o1.w = f2bf(r.w);
                }
                uint4 st;
                st.x = (unsigned)o0.x | ((unsigned)o0.y << 16);
                st.y = (unsigned)o0.z | ((unsigned)o0.w << 16);
                st.z = (unsigned)o1.x | ((unsigned)o1.y << 16);
                st.w = (unsigned)o1.z | ((unsigned)o1.w << 16);
                *(uint4*)(rhoh + (size_t)v * KP + c) = st;
            }
            continue;
        }
        const int gid = (u - CASTB) * 256 + tid;
        if (gid < 512) topicsumR[gid] = 0.f;
        if (gid == 520) *loss = 0.f;
        if (gid < 4 * 10 * 64 * 8) {
            int j = gid & 7;
            int ln = (gid >> 3) & 63;
            int rest = gid >> 9;
            int kt = rest % 10, w = rest / 10;
            int t = 16 * w + (ln & 15);
            int e = kt * 32 + (ln >> 4) * 8 + j;
            bfrag[gid] = (t < Tn && e < En) ? f2bf(alpha[t * En + e]) : (unsigned short)0;
        }
        if (gid < W1FRAG_N) {
            int j = gid & 7, ln = (gid >> 3) & 63, rest = gid >> 9;
            int kt = rest % 10, nt = rest / 10;
            int e = kt * 32 + (ln >> 4) * 8 + j;
            int hcol = nt * 16 + (ln & 15);
            w1frag[gid] = (e < En) ? f2bf(W1[e * Hn + hcol]) : (unsigned short)0;
        } else {
            int g2 = gid - W1FRAG_N;
            if (g2 < WFRAG_N) {
                int j = g2 & 7, ln = (g2 >> 3) & 63, rest = g2 >> 9;
                int kt = rest % 25, nt = rest / 25;
                int k = kt * 32 + (ln >> 4) * 8 + j;
                int t = (nt & 3) * 16 + (ln & 15);
                float val = 0.f;
                if (t < Tn) val = (nt < 4) ? Wmu[k * Tn + t] : Wlv[k * Tn + t];
                wfrag[g2] = f2bf(val);
            }
        }
    }
    grid.sync();

    // ---------------- P1: k4 betaU tiles + k1 gather ----------------
    for (int u = bid; u < P1UNITS; u += G) {
        __syncthreads();                 // LDS reuse guard between units
        if (u < K4B) {
            const int x = u & 7;         // XCD == slice (G multiple of 8)
            const int n = u >> 3;
            const int tile = ((x * 3125) >> 3) + n;
            if (tile >= (((x + 1) * 3125) >> 3)) continue;
            unsigned short* trans = (unsigned short*)smem;   // 16*66
            const int v0 = tile * 16;
            const unsigned short* arow = rhoh + (size_t)(v0 + l15) * KP + quad * 8;
            f32x4 acc = {0.f, 0.f, 0.f, 0.f};
            #pragma unroll
            for (int kt = 0; kt < 10; ++kt) {
                bf16x8 a = *(const bf16x8*)(arow + kt * 32);
                bf16x8 bv = *(const bf16x8*)(bfrag + ((wave * 10 + kt) * 64 + lane) * 8);
                acc = __builtin_amdgcn_mfma_f32_16x16x32_bf16(a, bv, acc, 0, 0, 0);
            }
            float ts = 0.f;
            #pragma unroll
            for (int r = 0; r < 4; ++r) {
                float ev = expf(acc[r]);
                ts += ev;
                trans[(quad * 4 + r) * 66 + 16 * wave + l15] = f2bf(ev);
            }
            ts += __shfl_xor(ts, 16, 64);
            ts += __shfl_xor(ts, 32, 64);
            const int t = 16 * wave + l15;
            if (lane < 16 && t < Tn)
                atomicAdd(&topicsumR[x * 64 + t], ts);
            __syncthreads();
            unsigned int* dst = betaU32 + (size_t)v0 * 32;
            const unsigned int* tr32 = (const unsigned int*)trans;
            for (int i = tid; i < 16 * 32; i += 256)
                dst[i] = tr32[(i >> 5) * 33 + (i & 31)];
            continue;
        }
        // k1 gather unit
        const int blk = u - K4B;
        const int r = blk & (NRANGE - 1), b = blk >> 3;
        const int lo = ((r * 3125) >> 3) * 16;
        const int hi = (((r + 1) * 3125) >> 3) * 16;
        int* sid = (int*)smem;                        // 512 ints
        int* sfid = sid + Sn;                         // 512 ints
        float* xred = (float*)(smem + 4096);          // 4*320 floats
        if (tid == 0) { scount = 0; sfull = 0; }
        __syncthreads();
        #pragma unroll
        for (int s0 = 0; s0 < Sn; s0 += 256) {
            int id = __builtin_nontemporal_load(&ids[b * Sn + s0 + tid]);
            bool val = (id != 1 && id != 2);
            bool inr = val && id >= lo && id < hi;
            unsigned long long mb = __ballot(inr);
            int pre = lane_prefix(mb);
            int wc = __popcll(mb);
            int base = 0;
            if (lane == 0 && wc) base = atomicAdd(&scount, wc);
            base = __shfl(base, 0, 64);
            if (inr) sid[base + pre] = id;
            if (r == 0) {
                unsigned long long fb = __ballot(val);
                int fpre = lane_prefix(fb);
                int fwc = __popcll(fb);
                int fbase = 0;
                if (lane == 0 && fwc) fbase = atomicAdd(&sfull, fwc);
                fbase = __shfl(fbase, 0, 64);
                if (val) sfid[fbase + fpre] = id;
            }
        }
        __syncthreads();
        if (r == 0) {
            const int nf = sfull;
            for (int i = tid; i < nf; i += 256) toks[b * Sn + i] = sfid[i];
            if (tid == 0) cnt[b] = nf;
        }
        const int m = scount;
        f32x2 c0 = {0.f, 0.f}, c1 = {0.f, 0.f}, c2 = {0.f, 0.f}, c3 = {0.f, 0.f};
        if (lane < 40) {
            const uint4* rb = (const uint4*)rhoh;
            int s = wave;
            for (; s + 12 < m; s += 16) {
                int i0 = sid[s], i1 = sid[s + 4], i2 = sid[s + 8], i3 = sid[s + 12];
                uint4 u0 = rb[(size_t)i0 * 40 + lane];
                uint4 u1 = rb[(size_t)i1 * 40 + lane];
                uint4 u2 = rb[(size_t)i2 * 40 + lane];
                uint4 u3 = rb[(size_t)i3 * 40 + lane];
                PKACC(u0); PKACC(u1); PKACC(u2); PKACC(u3);
            }
            for (; s < m; s += 4) {
                uint4 uq = rb[(size_t)sid[s] * 40 + lane];
                PKACC(uq);
            }
            float* xw = &xred[wave * 320 + lane * 8];
            *(float4*)(xw)     = (float4){c0[0], c0[1], c1[0], c1[1]};
            *(float4*)(xw + 4) = (float4){c2[0], c2[1], c3[0], c3[1]};
        }
        __syncthreads();
        float* xbp = xbarP + ((size_t)b * NRANGE + r) * KP;
        for (int c = tid; c < KP; c += 256)
            xbp[c] = xred[c] + xred[320 + c] + xred[640 + c] + xred[960 + c];
    }
    grid.sync();

    // ---------------- P2: xsg = bf16((sum_r xbarP)/n) ----------------
    for (int u = bid; u < 320; u += G) {
        const int i = u * 256 + tid;                  // < 81920
        const int b = i / (KP / 4), e4 = (i - b * (KP / 4)) * 4;
        const float in = 1.0f / (float)cnt[b];
        const float* bp = xbarP + ((size_t)b * NRANGE) * KP + e4;
        float sx = 0.f, sy = 0.f, sz = 0.f, sw_ = 0.f;
        #pragma unroll
        for (int rr = 0; rr < NRANGE; ++rr) {
            float4 v = *(const float4*)(bp + rr * KP);
            sx += v.x; sy += v.y; sz += v.z; sw_ += v.w;
        }
        ushort4 o;
        o.x = f2bf(sx * in); o.y = f2bf(sy * in);
        o.z = f2bf(sz * in); o.w = f2bf(sw_ * in);
        *(ushort4*)&xsg[(size_t)b * KP + e4] = o;
    }
    grid.sync();

    // ---------------- P3: hbh = bf16(relu(xsg@W1+b1)) ----------------
    for (int u = bid; u < 832; u += G) {
        __syncthreads();
        const int bx = u & 63, by = u >> 6;
        const int b0 = bx * 16;
        unsigned short* xs = (unsigned short*)smem;   // 16*328
        for (int i = tid; i < 16 * (KP / 8); i += 256) {
            int row = i / (KP / 8), e8 = (i - row * (KP / 8)) * 8;
            *(uint4*)&xs[row * 328 + e8] = *(const uint4*)&xsg[(size_t)(b0 + row) * KP + e8];
        }
        __syncthreads();
        const int nt = by * 4 + wave;
        if (nt < 50) {
            const unsigned short* arow = xs + l15 * 328 + quad * 8;
            f32x4 acc = {0.f, 0.f, 0.f, 0.f};
            #pragma unroll
            for (int kt = 0; kt < 10; ++kt) {
                bf16x8 a = *(const bf16x8*)(arow + kt * 32);
                bf16x8 bv = *(const bf16x8*)(w1frag + ((size_t)(nt * 10 + kt) * 64 + lane) * 8);
                acc = __builtin_amdgcn_mfma_f32_16x16x32_bf16(a, bv, acc, 0, 0, 0);
            }
            const int col = nt * 16 + l15;
            const float bias = b1[col];
            #pragma unroll
            for (int r = 0; r < 4; ++r) {
                int row = b0 + quad * 4 + r;
                hbh[(size_t)row * Hn + col] = f2bf(fmaxf(acc[r] + bias, 0.f));
            }
        }
    }
    grid.sync();

    // ---------------- P4: mu/lv MFMA -> softmax/theta/kl ----------------
    for (int u = bid; u < 64; u += G) {
        __syncthreads();
        float* mlds = (float*)smem;                   // 16*65
        float* llds = mlds + 16 * 65;                 // 16*65
        const int b0 = u * 16;
        const unsigned short* arow = hbh + (size_t)(b0 + l15) * Hn + quad * 8;
        f32x4 am = {0.f, 0.f, 0.f, 0.f}, al = {0.f, 0.f, 0.f, 0.f};
        #pragma unroll
        for (int kt = 0; kt < 25; ++kt) {
            bf16x8 a  = *(const bf16x8*)(arow + kt * 32);
            bf16x8 bm = *(const bf16x8*)(wfrag + ((size_t)(wave * 25 + kt) * 64 + lane) * 8);
            bf16x8 bl = *(const bf16x8*)(wfrag + ((size_t)((4 + wave) * 25 + kt) * 64 + lane) * 8);
            am = __builtin_amdgcn_mfma_f32_16x16x32_bf16(a, bm, am, 0, 0, 0);
            al = __builtin_amdgcn_mfma_f32_16x16x32_bf16(a, bl, al, 0, 0, 0);
        }
        const int t = wave * 16 + l15;
        const float bm_ = (t < Tn) ? bmu[t] : 0.f;
        const float bl_ = (t < Tn) ? blv[t] : 0.f;
        #pragma unroll
        for (int r = 0; r < 4; ++r) {
            int row = quad * 4 + r;
            mlds[row * 65 + t] = am[r] + bm_;
            llds[row * 65 + t] = al[r] + bl_;
        }
        __syncthreads();
        const int tt = (lane < Tn) ? lane : (Tn - 1);
        const bool act = (lane < Tn);
        float klacc = 0.f;
        #pragma unroll
        for (int k = 0; k < 4; ++k) {
            int row = wave * 4 + k;
            float mu = mlds[row * 65 + tt];
            float lv = llds[row * 65 + tt];
            float mx = waveReduceMax(act ? mu : -1e30f);
            float ex = act ? expf(mu - mx) : 0.f;
            float ssum = waveReduceSum(ex);
            if (act) theta[(b0 + row) * Tn + lane] = ex / ssum;
            klacc += waveReduceSum(act ? (1.f + lv - mu * mu - expf(lv)) : 0.f);
        }
        if (lane == 0) atomicAdd(loss, -0.5f * klacc * (1.0f / (float)Bn));
    }
    grid.sync();

    // ---------------- P5: recon loss ----------------
    const unsigned short* betaUh = (const unsigned short*)betaU32;
    for (int u = bid; u < Bn; u += G) {
        __syncthreads();
        float* sw = (float*)smem;                     // 52 floats
        float* swred = sw + 52;                       // 4 floats
        const int b = u;
        if (tid < 52) {
            float v = 0.f;
            if (tid < Tn) {
                float z = 0.f;
                #pragma unroll
                for (int j = 0; j < 8; ++j) z += topicsumR[j * 64 + tid];
                v = theta[b * Tn + tid] / z;
            }
            sw[tid] = v;
        }
        __syncthreads();
        float lsum = 0.f;
        const int n = cnt[b];
        for (int i = tid; i < n; i += 256) {
            int v = toks[b * Sn + i];
            const uint4* q = (const uint4*)(betaUh + (size_t)v * BSTR);
            float dot = 0.f;
            #pragma unroll
            for (int k = 0; k < 6; ++k) {
                uint4 uq = q[k];
                float4 w0 = *(const float4*)&sw[8 * k];
                float4 w1 = *(const float4*)&sw[8 * k + 4];
                dot += w0.x * bf_lo(uq.x) + w0.y * bf_hi(uq.x);
                dot += w0.z * bf_lo(uq.y) + w0.w * bf_hi(uq.y);
                dot += w1.x * bf_lo(uq.z) + w1.y * bf_hi(uq.z);
                dot += w1.z * bf_lo(uq.w) + w1.w * bf_hi(uq.w);
            }
            unsigned d = ((const unsigned*)q)[24];
            dot += sw[48] * bf_lo(d) + sw[49] * bf_hi(d);
            lsum += logf(dot + 1e-5f);
        }
        float s = waveReduceSum(lsum);
        if (lane == 0) swred[wave] = s;
        __syncthreads();
        if (tid == 0) {
            float tot = swred[0] + swred[1] + swred[2] + swred[3];
            atomicAdd(loss, -tot * (1.0f / (float)Bn));
        }
    }
}

extern "C" void kernel_launch(void* const* d_in, const int* in_sizes, int n_in,
                              void* d_out, int out_size, void* d_ws, size_t ws_size,
                              hipStream_t stream) {
    const int*    ids   = (const int*)d_in[0];
    const float4* rho4  = (const float4*)d_in[1];
    const float*  alpha = (const float*)d_in[2];
    const float*  W1    = (const float*)d_in[3];
    const float*  b1    = (const float*)d_in[4];
    const float*  Wmu   = (const float*)d_in[5];
    const float*  bmu   = (const float*)d_in[6];
    const float*  Wlv   = (const float*)d_in[7];
    const float*  blv   = (const float*)d_in[8];

    float* theta = (float*)d_out;            // [B, T]
    float* loss  = theta + Bn * Tn;          // scalar at d_out[51200]
    char*  ws    = (char*)d_ws;

    static int g_blocks = 0;
    if (g_blocks == 0) {
        int maxb = 0;
        hipOccupancyMaxActiveBlocksPerMultiprocessor(&maxb, kmega, 256, 0);
        if (maxb < 1) maxb = 1;
        long g = (long)maxb * 256;           // 256 CUs on MI355X
        if (g > 2048) g = 2048;
        g &= ~7L;                            // multiple of 8 for XCD affinity
        if (g < 8) g = 8;
        g_blocks = (int)g;
    }

    void* args[] = {
        (void*)&ids, (void*)&rho4, (void*)&alpha, (void*)&W1, (void*)&b1,
        (void*)&Wmu, (void*)&bmu, (void*)&Wlv, (void*)&blv,
        (void*)&theta, (void*)&loss, (void*)&ws
    };
    hipLaunchCooperativeKernel((void*)kmega, dim3(g_blocks), dim3(256),
                               args, 0, stream);
}

// Round 8
// 199.834 us; speedup vs baseline: 4.3233x; 4.3233x over previous
//
#include <hip/hip_runtime.h>
#include <math.h>

// ETM forward. B=1024 S=512 V=50000 E=300 H=800 T=50.
// ka2: zero topicsumR/loss + build alpha/W1/[Wmu|Wlv] MFMA B-frags (tiny)
// kb4: [fused cast+beta] per 16-vocab tile: load rho f32 -> bf16 LDS ->
//      MFMA betaU=exp(rhoh@alpha^T) + write rhoh slice. XCD-affine
//      (slice x on XCD x) so each XCD's L2 holds its 4MB rhoh slice warm.
// kb1: sliced token gather (slice r == XCD r, L2-warm rhoh), ballot
//      compaction, plain wave-token-parallel row loads -> xbarP partials.
// ktail: [kx+k2m+k3] per 16 docs: reduce xbarP -> x LDS -> h=relu(x@W1+b1)
//      LDS -> mu/lv MFMA -> softmax/theta/kl.
// k6: recon + loss.
// r7 lesson: cg::grid.sync() costs ~140us each at this grid -> persistent
// kernel ruled out. r0-r6 ledger: non-kb time ~145us invariant to work
// changes; kb's 55us invariant to depth/fetch -> split to isolate phases.

#define Bn 1024
#define Sn 512
#define Vn 50000
#define En 300
#define Hn 800
#define Tn 50
#define KP 320             // padded K for E-dim (10 tiles of 32)
#define BSTR 64            // betaU bf16 row stride (ushorts) = 128 B
#define W1FRAG_N (50 * 10 * 64 * 8)
#define WFRAG_N  (8 * 25 * 64 * 8)
#define NRANGE 8
#define K4B 3128                               // 8 x 391 (3125 tiles + 3 idle)

typedef __bf16 bf16x8 __attribute__((ext_vector_type(8)));
typedef float  f32x4  __attribute__((ext_vector_type(4)));
typedef float  f32x2  __attribute__((ext_vector_type(2)));

__device__ __forceinline__ float waveReduceSum(float v) {
    #pragma unroll
    for (int off = 32; off > 0; off >>= 1) v += __shfl_xor(v, off, 64);
    return v;
}
__device__ __forceinline__ float waveReduceMax(float v) {
    #pragma unroll
    for (int off = 32; off > 0; off >>= 1) v = fmaxf(v, __shfl_xor(v, off, 64));
    return v;
}
__device__ __forceinline__ unsigned short f2bf(float x) {
    unsigned u = __float_as_uint(x);
    return (unsigned short)((u + 0x7FFFu + ((u >> 16) & 1u)) >> 16);
}
__device__ __forceinline__ float bf_lo(unsigned u) { return __uint_as_float(u << 16); }
__device__ __forceinline__ float bf_hi(unsigned u) { return __uint_as_float(u & 0xFFFF0000u); }
__device__ __forceinline__ int lane_prefix(unsigned long long m) {
    return __builtin_amdgcn_mbcnt_hi((unsigned)(m >> 32),
           __builtin_amdgcn_mbcnt_lo((unsigned)m, 0));
}

#define PKACC(u) { \
    c0 += (f32x2){bf_lo((u).x), bf_hi((u).x)}; \
    c1 += (f32x2){bf_lo((u).y), bf_hi((u).y)}; \
    c2 += (f32x2){bf_lo((u).z), bf_hi((u).z)}; \
    c3 += (f32x2){bf_lo((u).w), bf_hi((u).w)}; }

// ka2: zero topicsumR/loss + build all MFMA B-frags. grid 1400.
__global__ __launch_bounds__(256) void ka2_init(
        const float* __restrict__ alpha, const float* __restrict__ W1,
        const float* __restrict__ Wmu, const float* __restrict__ Wlv,
        unsigned short* __restrict__ bfrag, unsigned short* __restrict__ w1frag,
        unsigned short* __restrict__ wfrag, float* __restrict__ topicsumR,
        float* __restrict__ loss) {
    const int gid = blockIdx.x * 256 + threadIdx.x;
    if (gid < 512) topicsumR[gid] = 0.f;
    if (gid == 520) *loss = 0.f;
    if (gid < 4 * 10 * 64 * 8) {
        int j = gid & 7;
        int lane = (gid >> 3) & 63;
        int rest = gid >> 9;               // w*10 + kt
        int kt = rest % 10, w = rest / 10;
        int t = 16 * w + (lane & 15);
        int e = kt * 32 + (lane >> 4) * 8 + j;
        bfrag[gid] = (t < Tn && e < En) ? f2bf(alpha[t * En + e]) : (unsigned short)0;
    }
    if (gid < W1FRAG_N) {
        int j = gid & 7, lane = (gid >> 3) & 63, rest = gid >> 9;
        int kt = rest % 10, nt = rest / 10;
        int e = kt * 32 + (lane >> 4) * 8 + j;
        int hcol = nt * 16 + (lane & 15);
        w1frag[gid] = (e < En) ? f2bf(W1[e * Hn + hcol]) : (unsigned short)0;
    } else {
        int g2 = gid - W1FRAG_N;
        if (g2 < WFRAG_N) {
            int j = g2 & 7, lane = (g2 >> 3) & 63, rest = g2 >> 9;
            int kt = rest % 25, nt = rest / 25;
            int k = kt * 32 + (lane >> 4) * 8 + j;        // < 800 always
            int t = (nt & 3) * 16 + (lane & 15);
            float val = 0.f;
            if (t < Tn) val = (nt < 4) ? Wmu[k * Tn + t] : Wlv[k * Tn + t];
            wfrag[g2] = f2bf(val);
        }
    }
}

// kb4: fused cast+beta per 16-vocab tile, XCD-affine. grid K4B=3128.
__global__ __launch_bounds__(256) void kb4_beta(
        const float* __restrict__ rho, unsigned short* __restrict__ rhoh,
        const unsigned short* __restrict__ bfrag,
        unsigned int* __restrict__ betaU32, float* __restrict__ topicsumR) {
    __shared__ __align__(16) unsigned short xs[16 * 328];   // 10496 B A-tile
    __shared__ unsigned short trans[16 * 66];               // 2112 B
    const int x = blockIdx.x & 7;            // XCD == slice
    const int n = blockIdx.x >> 3;           // 0..390
    const int tile = ((x * 3125) >> 3) + n;
    if (tile >= (((x + 1) * 3125) >> 3)) return;
    const int tid = threadIdx.x;
    const int wave = tid >> 6, lane = tid & 63;
    const int quad = lane >> 4, l15 = lane & 15;
    const int v0 = tile * 16;
    // stage: 16 rows x 300 f32 -> bf16 LDS (pad cols 300..319 with 0)
    for (int i = tid; i < 16 * 80; i += 256) {      // 80 float4-slots/row
        int row = i / 80, s4 = i - row * 80;
        ushort4 o = {0, 0, 0, 0};
        if (s4 < 75) {
            float4 r = *(const float4*)(rho + (size_t)(v0 + row) * En + s4 * 4);
            o.x = f2bf(r.x); o.y = f2bf(r.y); o.z = f2bf(r.z); o.w = f2bf(r.w);
        }
        *(ushort4*)&xs[row * 328 + s4 * 4] = o;
    }
    __syncthreads();
    // persist the bf16 tile to rhoh (coalesced 16B stores; write-allocates
    // this XCD's L2 slice, which kb1 on the same XCD re-reads ~10x)
    for (int i = tid; i < 16 * 40; i += 256) {
        int row = i / 40, c8 = (i - row * 40) * 8;
        *(uint4*)(rhoh + (size_t)(v0 + row) * KP + c8) = *(const uint4*)&xs[row * 328 + c8];
    }
    // betaU tile: wave = topic tile
    const unsigned short* arow = xs + l15 * 328 + quad * 8;
    f32x4 acc = {0.f, 0.f, 0.f, 0.f};
    #pragma unroll
    for (int kt = 0; kt < 10; ++kt) {
        bf16x8 a = *(const bf16x8*)(arow + kt * 32);
        bf16x8 bv = *(const bf16x8*)(bfrag + ((wave * 10 + kt) * 64 + lane) * 8);
        acc = __builtin_amdgcn_mfma_f32_16x16x32_bf16(a, bv, acc, 0, 0, 0);
    }
    float ts = 0.f;
    #pragma unroll
    for (int r = 0; r < 4; ++r) {
        float ev = expf(acc[r]);
        ts += ev;
        trans[(quad * 4 + r) * 66 + 16 * wave + l15] = f2bf(ev);
    }
    ts += __shfl_xor(ts, 16, 64);
    ts += __shfl_xor(ts, 32, 64);
    const int t = 16 * wave + l15;
    if (lane < 16 && t < Tn)
        atomicAdd(&topicsumR[x * 64 + t], ts);       // replica == XCD
    __syncthreads();
    unsigned int* dst = betaU32 + (size_t)v0 * 32;
    const unsigned int* tr32 = (const unsigned int*)trans;
    for (int i = tid; i < 16 * 32; i += 256)
        dst[i] = tr32[(i >> 5) * 33 + (i & 31)];
}

// kb1: sliced token gather. grid Bn*NRANGE = 8192; r = bid%8 == XCD.
__global__ __launch_bounds__(256) void kb1_gather(
        const unsigned short* __restrict__ rhoh, const int* __restrict__ ids,
        int* __restrict__ toks, int* __restrict__ cnt,
        float* __restrict__ xbarP) {
    __shared__ __align__(16) int sid[Sn];
    __shared__ int sfid[Sn];
    __shared__ __align__(16) float xred[4][320];
    __shared__ int scount, sfull;
    const int tid = threadIdx.x;
    const int wave = tid >> 6, lane = tid & 63;
    const int r = blockIdx.x & (NRANGE - 1), b = blockIdx.x >> 3;
    const int lo = ((r * 3125) >> 3) * 16;
    const int hi = (((r + 1) * 3125) >> 3) * 16;
    if (tid == 0) { scount = 0; sfull = 0; }
    __syncthreads();
    #pragma unroll
    for (int s0 = 0; s0 < Sn; s0 += 256) {
        int id = __builtin_nontemporal_load(&ids[b * Sn + s0 + tid]);
        bool val = (id != 1 && id != 2);
        bool inr = val && id >= lo && id < hi;
        unsigned long long mb = __ballot(inr);
        int pre = lane_prefix(mb);
        int wc = __popcll(mb);
        int base = 0;
        if (lane == 0 && wc) base = atomicAdd(&scount, wc);
        base = __shfl(base, 0, 64);
        if (inr) sid[base + pre] = id;
        if (r == 0) {
            unsigned long long fb = __ballot(val);
            int fpre = lane_prefix(fb);
            int fwc = __popcll(fb);
            int fbase = 0;
            if (lane == 0 && fwc) fbase = atomicAdd(&sfull, fwc);
            fbase = __shfl(fbase, 0, 64);
            if (val) sfid[fbase + fpre] = id;
        }
    }
    __syncthreads();
    if (r == 0) {
        const int nf = sfull;
        for (int i = tid; i < nf; i += 256) toks[b * Sn + i] = sfid[i];
        if (tid == 0) cnt[b] = nf;
    }
    const int m = scount;
    f32x2 c0 = {0.f, 0.f}, c1 = {0.f, 0.f}, c2 = {0.f, 0.f}, c3 = {0.f, 0.f};
    if (lane < 40) {
        const uint4* rb = (const uint4*)rhoh;
        int s = wave;
        for (; s + 12 < m; s += 16) {
            int i0 = sid[s], i1 = sid[s + 4], i2 = sid[s + 8], i3 = sid[s + 12];
            uint4 u0 = rb[(size_t)i0 * 40 + lane];
            uint4 u1 = rb[(size_t)i1 * 40 + lane];
            uint4 u2 = rb[(size_t)i2 * 40 + lane];
            uint4 u3 = rb[(size_t)i3 * 40 + lane];
            PKACC(u0); PKACC(u1); PKACC(u2); PKACC(u3);
        }
        for (; s < m; s += 4) {
            uint4 u = rb[(size_t)sid[s] * 40 + lane];
            PKACC(u);
        }
        float* xw = &xred[wave][lane * 8];
        *(float4*)(xw)     = (float4){c0[0], c0[1], c1[0], c1[1]};
        *(float4*)(xw + 4) = (float4){c2[0], c2[1], c3[0], c3[1]};
    }
    __syncthreads();
    float* xbp = xbarP + ((size_t)b * NRANGE + r) * KP;
    for (int c = tid; c < KP; c += 256)
        xbp[c] = xred[0][c] + xred[1][c] + xred[2][c] + xred[3][c];
}

// ktail: fused kx+k2m+k3, one block per 16 docs. grid 64.
__global__ __launch_bounds__(256) void ktail(
        const float* __restrict__ xbarP, const int* __restrict__ cnt,
        const unsigned short* __restrict__ w1frag, const float* __restrict__ b1,
        const unsigned short* __restrict__ wfrag,
        const float* __restrict__ bmu, const float* __restrict__ blv,
        float* __restrict__ theta, float* __restrict__ loss) {
    __shared__ unsigned short xs[16 * 328];    // 10496 B
    __shared__ unsigned short hs[16 * 808];    // 25856 B
    __shared__ float mlds[16 * 65];
    __shared__ float llds[16 * 65];
    __shared__ float invn[16];
    const int tid = threadIdx.x;
    const int wave = tid >> 6, lane = tid & 63;
    const int quad = lane >> 4, l15 = lane & 15;
    const int b0 = blockIdx.x * 16;
    if (tid < 16) invn[tid] = 1.0f / (float)cnt[b0 + tid];
    __syncthreads();
    for (int i = tid; i < 16 * (KP / 4); i += 256) {
        int row = i / (KP / 4), e4 = (i - row * (KP / 4)) * 4;
        const float* bp = xbarP + ((size_t)(b0 + row) * NRANGE) * KP + e4;
        float sx = 0.f, sy = 0.f, sz = 0.f, sw_ = 0.f;
        #pragma unroll
        for (int rr = 0; rr < NRANGE; ++rr) {
            float4 v = *(const float4*)(bp + rr * KP);
            sx += v.x; sy += v.y; sz += v.z; sw_ += v.w;
        }
        float in = invn[row];
        ushort4 o;
        o.x = f2bf(sx * in); o.y = f2bf(sy * in);
        o.z = f2bf(sz * in); o.w = f2bf(sw_ * in);
        *(ushort4*)&xs[row * 328 + e4] = o;
    }
    __syncthreads();
    {
        const unsigned short* arow = xs + l15 * 328 + quad * 8;
        for (int nt = wave; nt < 50; nt += 4) {
            f32x4 acc = {0.f, 0.f, 0.f, 0.f};
            #pragma unroll
            for (int kt = 0; kt < 10; ++kt) {
                bf16x8 a = *(const bf16x8*)(arow + kt * 32);
                bf16x8 bv = *(const bf16x8*)(w1frag + ((size_t)(nt * 10 + kt) * 64 + lane) * 8);
                acc = __builtin_amdgcn_mfma_f32_16x16x32_bf16(a, bv, acc, 0, 0, 0);
            }
            const int col = nt * 16 + l15;
            const float bias = b1[col];
            #pragma unroll
            for (int r = 0; r < 4; ++r)
                hs[(quad * 4 + r) * 808 + col] = f2bf(fmaxf(acc[r] + bias, 0.f));
        }
    }
    __syncthreads();
    {
        const unsigned short* arow = hs + l15 * 808 + quad * 8;
        f32x4 am = {0.f, 0.f, 0.f, 0.f}, al = {0.f, 0.f, 0.f, 0.f};
        #pragma unroll
        for (int kt = 0; kt < 25; ++kt) {
            bf16x8 a  = *(const bf16x8*)(arow + kt * 32);
            bf16x8 bm = *(const bf16x8*)(wfrag + ((size_t)(wave * 25 + kt) * 64 + lane) * 8);
            bf16x8 bl = *(const bf16x8*)(wfrag + ((size_t)((4 + wave) * 25 + kt) * 64 + lane) * 8);
            am = __builtin_amdgcn_mfma_f32_16x16x32_bf16(a, bm, am, 0, 0, 0);
            al = __builtin_amdgcn_mfma_f32_16x16x32_bf16(a, bl, al, 0, 0, 0);
        }
        const int t = wave * 16 + l15;
        const float bm_ = (t < Tn) ? bmu[t] : 0.f;
        const float bl_ = (t < Tn) ? blv[t] : 0.f;
        #pragma unroll
        for (int r = 0; r < 4; ++r) {
            int row = quad * 4 + r;
            mlds[row * 65 + t] = am[r] + bm_;
            llds[row * 65 + t] = al[r] + bl_;
        }
    }
    __syncthreads();
    const int tt = (lane < Tn) ? lane : (Tn - 1);
    const bool act = (lane < Tn);
    float klacc = 0.f;
    #pragma unroll
    for (int k = 0; k < 4; ++k) {
        int row = wave * 4 + k;
        float mu = mlds[row * 65 + tt];
        float lv = llds[row * 65 + tt];
        float m = waveReduceMax(act ? mu : -1e30f);
        float ex = act ? expf(mu - m) : 0.f;
        float ssum = waveReduceSum(ex);
        if (act) theta[(b0 + row) * Tn + lane] = ex / ssum;
        klacc += waveReduceSum(act ? (1.f + lv - mu * mu - expf(lv)) : 0.f);
    }
    if (lane == 0) atomicAdd(loss, -0.5f * klacc * (1.0f / (float)Bn));
}

// k6: recon loss. grid Bn.
__global__ __launch_bounds__(256) void k6_recon(
        const int* __restrict__ toks, const int* __restrict__ cnt,
        const float* __restrict__ theta, const float* __restrict__ topicsumR,
        const unsigned short* __restrict__ betaUh, float* __restrict__ loss) {
    __shared__ float sw[Tn];
    __shared__ float swred[4];
    const int b = blockIdx.x, tid = threadIdx.x;
    if (tid < Tn) {
        float z = 0.f;
        #pragma unroll
        for (int j = 0; j < 8; ++j) z += topicsumR[j * 64 + tid];
        sw[tid] = theta[b * Tn + tid] / z;
    }
    __syncthreads();
    float wr[Tn];
    #pragma unroll
    for (int t = 0; t < Tn; ++t) wr[t] = sw[t];
    float lsum = 0.f;
    const int n = cnt[b];
    for (int i = tid; i < n; i += 256) {
        int v = toks[b * Sn + i];
        const uint4* q = (const uint4*)(betaUh + (size_t)v * BSTR);
        float dot = 0.f;
        #pragma unroll
        for (int k = 0; k < 6; ++k) {
            uint4 u = q[k];
            int t = 8 * k;
            dot += wr[t]     * bf_lo(u.x) + wr[t + 1] * bf_hi(u.x);
            dot += wr[t + 2] * bf_lo(u.y) + wr[t + 3] * bf_hi(u.y);
            dot += wr[t + 4] * bf_lo(u.z) + wr[t + 5] * bf_hi(u.z);
            dot += wr[t + 6] * bf_lo(u.w) + wr[t + 7] * bf_hi(u.w);
        }
        unsigned d = ((const unsigned*)q)[24];
        dot += wr[48] * bf_lo(d) + wr[49] * bf_hi(d);
        lsum += logf(dot + 1e-5f);
    }
    float s = waveReduceSum(lsum);
    const int wave = tid >> 6, lane = tid & 63;
    if (lane == 0) swred[wave] = s;
    __syncthreads();
    if (tid == 0) {
        float tot = swred[0] + swred[1] + swred[2] + swred[3];
        atomicAdd(loss, -tot * (1.0f / (float)Bn));
    }
}

extern "C" void kernel_launch(void* const* d_in, const int* in_sizes, int n_in,
                              void* d_out, int out_size, void* d_ws, size_t ws_size,
                              hipStream_t stream) {
    const int*   ids   = (const int*)d_in[0];
    const float* rho   = (const float*)d_in[1];
    const float* alpha = (const float*)d_in[2];
    const float* W1    = (const float*)d_in[3];
    const float* b1    = (const float*)d_in[4];
    const float* Wmu   = (const float*)d_in[5];
    const float* bmu   = (const float*)d_in[6];
    const float* Wlv   = (const float*)d_in[7];
    const float* blv   = (const float*)d_in[8];

    float* theta = (float*)d_out;            // [B, T]
    float* loss  = theta + Bn * Tn;          // scalar at d_out[51200]

    char* w = (char*)d_ws;
    float* topicsumR = (float*)w;               w += 8 * 64 * 4;
    unsigned short* bfrag = (unsigned short*)w; w += 4 * 10 * 64 * 8 * 2;
    unsigned short* w1frag = (unsigned short*)w; w += (size_t)W1FRAG_N * 2;
    unsigned short* wfrag = (unsigned short*)w;  w += (size_t)WFRAG_N * 2;
    int*   cnt      = (int*)w;                  w += Bn * 4;
    int*   toks     = (int*)w;                  w += Bn * Sn * 4;
    float* xbarP    = (float*)w;                w += (size_t)Bn * NRANGE * KP * 4; // 10.5 MB
    unsigned short* rhoh = (unsigned short*)w;  w += (size_t)Vn * KP * 2;   // 32 MB
    unsigned int* betaU32 = (unsigned int*)w;   w += (size_t)Vn * 128;      // 6.4 MB

    const int k0grid = (W1FRAG_N + WFRAG_N + 255) / 256;   // 1400
    ka2_init<<<k0grid, 256, 0, stream>>>(
        alpha, W1, Wmu, Wlv, bfrag, w1frag, wfrag, topicsumR, loss);
    kb4_beta<<<K4B, 256, 0, stream>>>(rho, rhoh, bfrag, betaU32, topicsumR);
    kb1_gather<<<Bn * NRANGE, 256, 0, stream>>>(rhoh, ids, toks, cnt, xbarP);
    ktail<<<64, 256, 0, stream>>>(xbarP, cnt, w1frag, b1, wfrag, bmu, blv,
                                  theta, loss);
    k6_recon<<<Bn, 256, 0, stream>>>(toks, cnt, theta, topicsumR,
                                     (const unsigned short*)betaU32, loss);
}